// Round 2
// baseline (1150.169 us; speedup 1.0000x reference)
//
#include <hip/hip_runtime.h>
#include <stdint.h>

// MemoryModule: z[N=65536,D=256], memory[M=2000,D=256] (fp32)
//   z_norm, m_norm = row-L2-normalize (eps added to norm)
//   sim = z_norm @ m_norm^T   [N,M]
//   w = softmax(sim, axis=1)
//   w2 = relu(w-lamb)*w/(|w-lamb|+1e-12); w_hat = w2/(sum w2 + 1e-12)
//   z_hat = w_hat @ memory    [N,D]
// d_out = [z_hat (N*D) | w_hat (N*M)] fp32

typedef float  f32x4  __attribute__((ext_vector_type(4)));
typedef __bf16 bf16x8 __attribute__((ext_vector_type(8)));

#define DDIM 256
#define MDIM 2000
#define MT   125          // 2000 / 16 m-tiles
#define MPAD 2048
#define LAMB 0.002f
#define EPS_NORM 1e-10f
#define EPS_SHRINK 1e-12f

// ---------------- kernel 1: memory -> bf16 m_norm (padded to MPAD rows) ----
__global__ __launch_bounds__(256) void norm_mem_k(const float* __restrict__ mem,
                                                  __bf16* __restrict__ mnorm) {
  const int row = blockIdx.x;
  const int t   = threadIdx.x;
  if (row >= MDIM) { mnorm[(size_t)row * DDIM + t] = (__bf16)0.0f; return; }
  float x = mem[(size_t)row * DDIM + t];
  float s = x * x;
  #pragma unroll
  for (int m = 1; m < 64; m <<= 1) s += __shfl_xor(s, m, 64);
  __shared__ float wsum[4];
  if ((t & 63) == 0) wsum[t >> 6] = s;
  __syncthreads();
  s = wsum[0] + wsum[1] + wsum[2] + wsum[3];
  const float scale = 1.0f / (sqrtf(s) + EPS_NORM);
  mnorm[(size_t)row * DDIM + t] = (__bf16)(x * scale);
}

// ---------------- kernel 2: fused per-16-row block ------------------------
// block = 256 threads (4 waves). Each block owns 16 z-rows.
// Wave w owns CONTIGUOUS tiles [w*32, min(w*32+32, 125)) -> m-cols [w*512, ...).
// sim tile kept in registers: 32 x f32x4 per lane (MFMA C layout:
// col = lane&15 (m within tile), row = (lane>>4)*4 + reg (n within 16)).
// w_hat stores are staged through LDS (per-wave 16x128 chunk, stride 132)
// and written as coalesced float4 (512B contiguous per 32-lane half-wave).
__global__ __launch_bounds__(256, 2) void fused_k(
    const float* __restrict__ z, const __bf16* __restrict__ mnorm,
    const float* __restrict__ mem, float* __restrict__ outz,
    float* __restrict__ outw) {
  __shared__ __bf16 zs[16][264];   // +8 bf16 pad per row
  __shared__ float  red[4][16];
  __shared__ float  pool[4 * 16 * 132];  // per-wave w_hat staging; unioned w/ zacc
  __shared__ int    anyflag;

  const int tid  = threadIdx.x;
  const int n0   = blockIdx.x * 16;
  const int lane = tid & 63;
  const int wave = tid >> 6;
  const int quad = lane >> 4;
  const int col  = lane & 15;

  #define SWT(wv, r, c) pool[(((wv) * 16 + (r)) * 132) + (c)]

  if (tid == 0) anyflag = 0;

  // ---- phase 1: z_norm -> zs (bf16). thread = (row tid>>4, 16 cols) ----
  {
    const int r  = tid >> 4;
    const int c0 = (tid & 15) * 16;
    const float* zp = z + (size_t)(n0 + r) * DDIM + c0;
    float v[16];
    #pragma unroll
    for (int k = 0; k < 4; ++k) {
      const float4 q = *(const float4*)(zp + 4 * k);
      v[4*k+0] = q.x; v[4*k+1] = q.y; v[4*k+2] = q.z; v[4*k+3] = q.w;
    }
    float s = 0.f;
    #pragma unroll
    for (int k = 0; k < 16; ++k) s += v[k] * v[k];
    #pragma unroll
    for (int m = 1; m < 16; m <<= 1) s += __shfl_xor(s, m, 64);
    const float scale = 1.0f / (sqrtf(s) + EPS_NORM);
    #pragma unroll
    for (int k = 0; k < 16; ++k) zs[r][c0 + k] = (__bf16)(v[k] * scale);
  }
  __syncthreads();

  // ---- phase 2: A-fragments (z side) from LDS, then MFMA over m-tiles ----
  bf16x8 af[8];
  #pragma unroll
  for (int kc = 0; kc < 8; ++kc)
    af[kc] = *(const bf16x8*)&zs[col][kc * 32 + quad * 8];

  f32x4 acc[32];
  #pragma unroll
  for (int i = 0; i < 32; ++i) acc[i] = (f32x4){0.f, 0.f, 0.f, 0.f};

  #pragma unroll
  for (int i = 0; i < 32; ++i) {
    const int t = wave * 32 + i;
    if (t < MT) {
      const __bf16* bp = mnorm + (size_t)(t * 16 + col) * DDIM + quad * 8;
      bf16x8 b[8];
      #pragma unroll
      for (int kc = 0; kc < 8; ++kc) b[kc] = *(const bf16x8*)(bp + kc * 32);
      f32x4 c = acc[i];
      #pragma unroll
      for (int kc = 0; kc < 8; ++kc)
        c = __builtin_amdgcn_mfma_f32_16x16x32_bf16(af[kc], b[kc], c, 0, 0, 0);
      acc[i] = c;
    }
  }

  // ---- phase 3a: row max ----
  float rmax[4];
  {
    float lm[4];
    #pragma unroll
    for (int j = 0; j < 4; ++j) lm[j] = -1e30f;
    #pragma unroll
    for (int i = 0; i < 32; ++i) {
      const int t = wave * 32 + i;
      if (t < MT) {
        #pragma unroll
        for (int j = 0; j < 4; ++j) lm[j] = fmaxf(lm[j], acc[i][j]);
      }
    }
    #pragma unroll
    for (int j = 0; j < 4; ++j) {
      #pragma unroll
      for (int m = 1; m < 16; m <<= 1) lm[j] = fmaxf(lm[j], __shfl_xor(lm[j], m, 64));
    }
    if (col == 0) {
      #pragma unroll
      for (int j = 0; j < 4; ++j) red[wave][quad * 4 + j] = lm[j];
    }
    __syncthreads();
    #pragma unroll
    for (int j = 0; j < 4; ++j) {
      const int r = quad * 4 + j;
      rmax[j] = fmaxf(fmaxf(red[0][r], red[1][r]), fmaxf(red[2][r], red[3][r]));
    }
    __syncthreads();
  }

  // ---- phase 3b: exp + row sum (overwrite acc with exp values) ----
  float rsum[4];
  {
    float ls[4] = {0.f, 0.f, 0.f, 0.f};
    #pragma unroll
    for (int i = 0; i < 32; ++i) {
      const int t = wave * 32 + i;
      if (t < MT) {
        #pragma unroll
        for (int j = 0; j < 4; ++j) {
          const float e = __expf(acc[i][j] - rmax[j]);
          acc[i][j] = e;
          ls[j] += e;
        }
      }
    }
    #pragma unroll
    for (int j = 0; j < 4; ++j) {
      #pragma unroll
      for (int m = 1; m < 16; m <<= 1) ls[j] += __shfl_xor(ls[j], m, 64);
    }
    if (col == 0) {
      #pragma unroll
      for (int j = 0; j < 4; ++j) red[wave][quad * 4 + j] = ls[j];
    }
    __syncthreads();
    #pragma unroll
    for (int j = 0; j < 4; ++j) {
      const int r = quad * 4 + j;
      rsum[j] = red[0][r] + red[1][r] + red[2][r] + red[3][r];
    }
    __syncthreads();
  }

  // ---- phase 3c: w, hard-shrink, shrink-sum (overwrite acc with w2) ----
  float rs2[4];
  {
    float inv[4];
    #pragma unroll
    for (int j = 0; j < 4; ++j) inv[j] = 1.0f / rsum[j];
    float ls[4] = {0.f, 0.f, 0.f, 0.f};
    #pragma unroll
    for (int i = 0; i < 32; ++i) {
      const int t = wave * 32 + i;
      if (t < MT) {
        #pragma unroll
        for (int j = 0; j < 4; ++j) {
          const float w = acc[i][j] * inv[j];
          const float d = w - LAMB;
          float w2 = 0.f;
          if (d > 0.f) { w2 = d * w / (d + EPS_SHRINK); anyflag = 1; }
          acc[i][j] = w2;
          ls[j] += w2;
        }
      }
    }
    #pragma unroll
    for (int j = 0; j < 4; ++j) {
      #pragma unroll
      for (int m = 1; m < 16; m <<= 1) ls[j] += __shfl_xor(ls[j], m, 64);
    }
    if (col == 0) {
      #pragma unroll
      for (int j = 0; j < 4; ++j) red[wave][quad * 4 + j] = ls[j];
    }
    __syncthreads();
    #pragma unroll
    for (int j = 0; j < 4; ++j) {
      const int r = quad * 4 + j;
      rs2[j] = red[0][r] + red[1][r] + red[2][r] + red[3][r];
    }
  }

  // ---- phase 3d: w_hat = w2/(s2+eps); LDS-staged coalesced stores ----
  #pragma unroll
  for (int j = 0; j < 4; ++j) rs2[j] = 1.0f / (rs2[j] + EPS_SHRINK);

  const int wbase = wave * 512;          // first m-col owned by this wave
  #pragma unroll
  for (int c = 0; c < 4; ++c) {
    // scatter 8 tiles' w_hat into this wave's LDS chunk (16 x 128, stride 132)
    #pragma unroll
    for (int i8 = 0; i8 < 8; ++i8) {
      const int i = c * 8 + i8;
      const int t = wave * 32 + i;
      if (t < MT) {
        #pragma unroll
        for (int j = 0; j < 4; ++j) {
          const float wh = acc[i][j] * rs2[j];
          acc[i][j] = wh;                       // keep for z_hat sparse path
          SWT(wave, quad * 4 + j, i8 * 16 + col) = wh;
        }
      }
    }
    // coalesced write-back: 2 rows per iteration, 32 lanes x float4 per row
    const int halfrow = lane >> 5;       // 0 or 1
    const int colf    = (lane & 31) * 4; // 0..124
    #pragma unroll
    for (int rr = 0; rr < 16; rr += 2) {
      const int row = rr + halfrow;
      const int gm  = wbase + c * 128 + colf;
      if (gm < MDIM) {
        const f32x4 v = *(const f32x4*)&SWT(wave, row, colf);
        *(f32x4*)(outw + (size_t)(n0 + row) * MDIM + gm) = v;
      }
    }
  }

  __syncthreads();   // anyflag settled; pool free for reuse as zacc

  // ---- phase 4: z_hat. Sparse path only if any weight survived. ----
  if (anyflag == 0) {
    const float4 z4 = {0.f, 0.f, 0.f, 0.f};
    float4* oz = (float4*)(outz + (size_t)n0 * DDIM);
    #pragma unroll
    for (int k = 0; k < 4; ++k) oz[tid + 256 * k] = z4;
  } else {
    float (*zacc)[DDIM] = (float (*)[DDIM])pool;   // 16 x 256 floats
    for (int idx = tid; idx < 16 * DDIM; idx += 256) pool[idx] = 0.f;
    __syncthreads();
    #pragma unroll
    for (int i = 0; i < 32; ++i) {
      const int t = wave * 32 + i;
      if (t < MT) {
        #pragma unroll
        for (int j = 0; j < 4; ++j) {
          const float wh = acc[i][j];
          if (wh > 0.f) {
            const float* mrow = mem + (size_t)(t * 16 + col) * DDIM;
            float* zr = &zacc[quad * 4 + j][0];
            for (int dd = 0; dd < DDIM; ++dd) atomicAdd(&zr[dd], wh * mrow[dd]);
          }
        }
      }
    }
    __syncthreads();
    const int r  = tid >> 4;
    const int c0 = (tid & 15) * 16;
    #pragma unroll
    for (int k = 0; k < 4; ++k)
      *(float4*)(outz + (size_t)(n0 + r) * DDIM + c0 + 4 * k) =
          *(float4*)&zacc[r][c0 + 4 * k];
  }
}

extern "C" void kernel_launch(void* const* d_in, const int* in_sizes, int n_in,
                              void* d_out, int out_size, void* d_ws, size_t ws_size,
                              hipStream_t stream) {
  const float* z   = (const float*)d_in[0];
  const float* mem = (const float*)d_in[1];
  const int N = in_sizes[0] / DDIM;           // 65536
  float* outz = (float*)d_out;                // [N, D]
  float* outw = outz + (size_t)N * DDIM;      // [N, M]
  __bf16* mnorm = (__bf16*)d_ws;              // [MPAD, D] bf16 = 1 MiB

  hipLaunchKernelGGL(norm_mem_k, dim3(MPAD), dim3(DDIM), 0, stream, mem, mnorm);
  hipLaunchKernelGGL(fused_k, dim3(N / 16), dim3(256), 0, stream,
                     z, mnorm, mem, outz, outw);
}

// Round 3
// 1059.548 us; speedup vs baseline: 1.0855x; 1.0855x over previous
//
#include <hip/hip_runtime.h>
#include <stdint.h>

// MemoryModule: z[N=65536,D=256], memory[M=2000,D=256] (fp32)
//   z_norm, m_norm = row-L2-normalize (eps added to norm)
//   sim = z_norm @ m_norm^T; w = softmax(sim, axis=1)
//   w2 = relu(w-lamb)*w/(|w-lamb|+1e-12); w_hat = w2/(sum w2 + 1e-12)
//   z_hat = w_hat @ memory
// d_out = [z_hat (N*D) | w_hat (N*M)] fp32
//
// R2 design: 2-sweep recompute, 32 z-rows/block, no AGPR hoard.
// Softmax max-subtraction dropped: |sim| <= ~1 (cosine), exp in [0.37, 2.72],
// mathematically identical w. Sweep1: S = sum(exp). Sweep2: recompute sim,
// w2 + S2 + store. Correction pass only if S2 != 0 (general correctness).

typedef float  f32x4  __attribute__((ext_vector_type(4)));
typedef __bf16 bf16x8 __attribute__((ext_vector_type(8)));

#define DDIM 256
#define MDIM 2000
#define MT   125          // 2000 / 16 m-tiles
#define MPAD 2048
#define NROWS 32          // z-rows per block (2 row-groups of 16)
#define LAMB 0.002f
#define EPS_NORM 1e-10f
#define EPS_SHRINK 1e-12f

// ---------------- kernel 1: memory -> bf16 m_norm (padded to MPAD rows) ----
__global__ __launch_bounds__(256) void norm_mem_k(const float* __restrict__ mem,
                                                  __bf16* __restrict__ mnorm) {
  const int row = blockIdx.x;
  const int t   = threadIdx.x;
  if (row >= MDIM) { mnorm[(size_t)row * DDIM + t] = (__bf16)0.0f; return; }
  float x = mem[(size_t)row * DDIM + t];
  float s = x * x;
  #pragma unroll
  for (int m = 1; m < 64; m <<= 1) s += __shfl_xor(s, m, 64);
  __shared__ float wsum[4];
  if ((t & 63) == 0) wsum[t >> 6] = s;
  __syncthreads();
  s = wsum[0] + wsum[1] + wsum[2] + wsum[3];
  const float scale = 1.0f / (sqrtf(s) + EPS_NORM);
  mnorm[(size_t)row * DDIM + t] = (__bf16)(x * scale);
}

// ---------------- kernel 2: fused, 32 rows/block, 2 sweeps ----------------
// 4 waves split 125 m-tiles contiguously (32 per wave). Each tile:
// B[8] (16 rows x K=256 bf16) from L2, MFMA vs 2 row-group A-frags (regs).
// MFMA C layout (16x16x32): col = lane&15 (m), row = quad*4 + reg (n).
__global__ __launch_bounds__(256, 3) void fused_k(
    const float* __restrict__ z, const __bf16* __restrict__ mnorm,
    const float* __restrict__ mem, float* __restrict__ outz,
    float* __restrict__ outw) {
  __shared__ __bf16 zs[NROWS][264];      // z_norm staging (+8 pad)
  __shared__ float  red[4][NROWS];       // cross-wave row reduction
  __shared__ float  Srow[NROWS];         // softmax denominators
  __shared__ float  S2row[NROWS];        // shrink-sum per row
  __shared__ float  zacc[NROWS][DDIM];   // z_hat accumulator (rare path)

  const int tid  = threadIdx.x;
  const int n0   = blockIdx.x * NROWS;
  const int lane = tid & 63;
  const int wave = tid >> 6;
  const int quad = lane >> 4;
  const int col  = lane & 15;

  // ---- phase 1: z_norm -> zs. thread = (row tid>>3, 32 cols) ----
  {
    const int r  = tid >> 3;
    const int c0 = (tid & 7) * 32;
    const float* zp = z + (size_t)(n0 + r) * DDIM + c0;
    float v[32];
    #pragma unroll
    for (int k = 0; k < 8; ++k) {
      const float4 q = *(const float4*)(zp + 4 * k);
      v[4*k+0] = q.x; v[4*k+1] = q.y; v[4*k+2] = q.z; v[4*k+3] = q.w;
    }
    float s = 0.f;
    #pragma unroll
    for (int k = 0; k < 32; ++k) s += v[k] * v[k];
    #pragma unroll
    for (int m = 1; m < 8; m <<= 1) s += __shfl_xor(s, m, 64);
    const float scale = 1.0f / (sqrtf(s) + EPS_NORM);
    #pragma unroll
    for (int k = 0; k < 32; ++k) zs[r][c0 + k] = (__bf16)(v[k] * scale);
  }
  // zero zacc (always; atomics into it only on the rare shrink-survivor path)
  for (int idx = tid; idx < NROWS * DDIM; idx += 256) ((float*)zacc)[idx] = 0.f;
  __syncthreads();

  // ---- A fragments for both row-groups (64 VGPR, live whole kernel) ----
  bf16x8 af[2][8];
  #pragma unroll
  for (int rg = 0; rg < 2; ++rg)
    #pragma unroll
    for (int kc = 0; kc < 8; ++kc)
      af[rg][kc] = *(const bf16x8*)&zs[rg * 16 + col][kc * 32 + quad * 8];

  const int t0 = wave * 32;

  // ---- sweep 1: S = sum(exp(sim)) per row ----
  float S[2][4] = {{0.f,0.f,0.f,0.f},{0.f,0.f,0.f,0.f}};
  for (int i = 0; i < 32; ++i) {
    const int t = t0 + i;
    if (t >= MT) break;                      // wave-uniform
    const __bf16* bp = mnorm + (size_t)(t * 16 + col) * DDIM + quad * 8;
    bf16x8 b[8];
    #pragma unroll
    for (int kc = 0; kc < 8; ++kc) b[kc] = *(const bf16x8*)(bp + kc * 32);
    #pragma unroll
    for (int rg = 0; rg < 2; ++rg) {
      f32x4 c = (f32x4){0.f, 0.f, 0.f, 0.f};
      #pragma unroll
      for (int kc = 0; kc < 8; ++kc)
        c = __builtin_amdgcn_mfma_f32_16x16x32_bf16(af[rg][kc], b[kc], c, 0, 0, 0);
      #pragma unroll
      for (int j = 0; j < 4; ++j) S[rg][j] += __expf(c[j]);
    }
  }
  #pragma unroll
  for (int rg = 0; rg < 2; ++rg)
    #pragma unroll
    for (int j = 0; j < 4; ++j) {
      #pragma unroll
      for (int m = 1; m < 16; m <<= 1) S[rg][j] += __shfl_xor(S[rg][j], m, 64);
      if (col == 0) red[wave][rg * 16 + quad * 4 + j] = S[rg][j];
    }
  __syncthreads();
  if (tid < NROWS) Srow[tid] = red[0][tid] + red[1][tid] + red[2][tid] + red[3][tid];
  __syncthreads();

  float invS[2][4];
  #pragma unroll
  for (int rg = 0; rg < 2; ++rg)
    #pragma unroll
    for (int j = 0; j < 4; ++j) invS[rg][j] = 1.0f / Srow[rg * 16 + quad * 4 + j];

  // ---- sweep 2: recompute sim; w2, S2, store w2 (w_hat if S2==0) ----
  float S2[2][4] = {{0.f,0.f,0.f,0.f},{0.f,0.f,0.f,0.f}};
  for (int i = 0; i < 32; ++i) {
    const int t = t0 + i;
    if (t >= MT) break;
    const __bf16* bp = mnorm + (size_t)(t * 16 + col) * DDIM + quad * 8;
    bf16x8 b[8];
    #pragma unroll
    for (int kc = 0; kc < 8; ++kc) b[kc] = *(const bf16x8*)(bp + kc * 32);
    #pragma unroll
    for (int rg = 0; rg < 2; ++rg) {
      f32x4 c = (f32x4){0.f, 0.f, 0.f, 0.f};
      #pragma unroll
      for (int kc = 0; kc < 8; ++kc)
        c = __builtin_amdgcn_mfma_f32_16x16x32_bf16(af[rg][kc], b[kc], c, 0, 0, 0);
      #pragma unroll
      for (int j = 0; j < 4; ++j) {
        const float w = __expf(c[j]) * invS[rg][j];
        const float d = w - LAMB;
        float w2 = 0.f;
        if (d > 0.f) {                       // never for this data; general path
          w2 = d * w / (d + EPS_SHRINK);
          const float* mrow = mem + (size_t)(t * 16 + col) * DDIM;
          float* zr = &zacc[rg * 16 + quad * 4 + j][0];
          for (int dd = 0; dd < DDIM; ++dd) atomicAdd(&zr[dd], w2 * mrow[dd]);
        }
        S2[rg][j] += w2;
        outw[(size_t)(n0 + rg * 16 + quad * 4 + j) * MDIM + t * 16 + col] = w2;
      }
    }
  }
  #pragma unroll
  for (int rg = 0; rg < 2; ++rg)
    #pragma unroll
    for (int j = 0; j < 4; ++j) {
      #pragma unroll
      for (int m = 1; m < 16; m <<= 1) S2[rg][j] += __shfl_xor(S2[rg][j], m, 64);
      if (col == 0) red[wave][rg * 16 + quad * 4 + j] = S2[rg][j];
    }
  __syncthreads();
  if (tid < NROWS) S2row[tid] = red[0][tid] + red[1][tid] + red[2][tid] + red[3][tid];
  __syncthreads();

  float totS2 = 0.f;
  #pragma unroll
  for (int r = 0; r < NROWS; ++r) totS2 += S2row[r];

  // ---- correction pass (only if some weight survived shrink; exact) ----
  if (totS2 > 0.f) {
    #pragma unroll 1
    for (int i = 0; i < 32; ++i) {
      const int t = t0 + i;
      if (t >= MT) break;
      for (int rg = 0; rg < 2; ++rg)
        for (int j = 0; j < 4; ++j) {
          const int r = rg * 16 + quad * 4 + j;
          const float rs2 = 1.0f / (S2row[r] + EPS_SHRINK);
          float* p = outw + (size_t)(n0 + r) * MDIM + t * 16 + col;
          *p = *p * rs2;                     // w2==0 rows: 0*big == 0, exact
        }
    }
  }

  // ---- z_hat epilogue ----
  if (totS2 == 0.f) {
    float4 zero4 = {0.f, 0.f, 0.f, 0.f};
    float4* oz = (float4*)(outz + (size_t)n0 * DDIM);
    #pragma unroll
    for (int k = 0; k < 8; ++k) oz[tid + 256 * k] = zero4;
  } else {
    const int r  = tid >> 3;
    const int c0 = (tid & 7) * 32;
    const float rs2 = 1.0f / (S2row[r] + EPS_SHRINK);
    #pragma unroll
    for (int k = 0; k < 8; ++k) {
      f32x4 v = *(const f32x4*)&zacc[r][c0 + 4 * k];
      v *= rs2;
      *(f32x4*)(outz + (size_t)(n0 + r) * DDIM + c0 + 4 * k) = v;
    }
  }
}

extern "C" void kernel_launch(void* const* d_in, const int* in_sizes, int n_in,
                              void* d_out, int out_size, void* d_ws, size_t ws_size,
                              hipStream_t stream) {
  const float* z   = (const float*)d_in[0];
  const float* mem = (const float*)d_in[1];
  const int N = in_sizes[0] / DDIM;           // 65536
  float* outz = (float*)d_out;                // [N, D]
  float* outw = outz + (size_t)N * DDIM;      // [N, M]
  __bf16* mnorm = (__bf16*)d_ws;              // [MPAD, D] bf16 = 1 MiB

  hipLaunchKernelGGL(norm_mem_k, dim3(MPAD), dim3(DDIM), 0, stream, mem, mnorm);
  hipLaunchKernelGGL(fused_k, dim3(N / NROWS), dim3(256), 0, stream,
                     z, mnorm, mem, outz, outw);
}